// Round 10
// baseline (181.701 us; speedup 1.0000x reference)
//
#include <hip/hip_runtime.h>
#include <hip/hip_bf16.h>

#define GK 512
#define GN 128
#define GRROWS 131072   // 4096 batch * 32 blocks

typedef float  f32x4  __attribute__((ext_vector_type(4)));
typedef __bf16 bf16x8 __attribute__((ext_vector_type(8)));
typedef unsigned int u32x4 __attribute__((ext_vector_type(4)));

// ---------------------------------------------------------------------------
// Single fused kernel.
// Grid 512 x 512 thr (8 waves) -> exactly 2 blocks/CU, all resident in one
// round (no block turnover, no second dispatch, no inter-kernel gap).
//
// Prologue: each block builds the k<256 HALF of W's MFMA fragments in LDS
// (64 KB) directly from p_values (~64 transcendentals/thread ~ 0.3 us):
//   lw[t][f][lane][j], t=0..7, f=0..7:
//     W[k][n], n = f*16+(lane&15), g=lane>>4, k = t*32+(j>>2)*16+g*4+(j&3)
//     (k-slot permutation applied identically to the X fragment ->
//      contraction unchanged; makes X loads cover full 64B lines)
//   W[k][n]=A[n][k]: k<256: n<64 -> cos, n>=64 -> sin,
//     ang = -2pi*pv[n&63]*k/256  ->  arg = ang/pi = pv*k*(-1/128)
// Symmetry (k->k+256 flips quadrant): frag_full(t+8,f) = -frag(t,f+4) [f<4],
//                                     frag_full(t+8,f) = +frag(t,f-4) [f>=4]
//
// Main loop (R8-proven, no spill): per stripe (2 stripes of 128 rows,
// #pragma unroll 1 so frag ds_reads are NOT CSE'd across stripes - R7
// lesson), one loop over t=0..7 handles K-steps t AND t+8 so each LDS
// fragment is read once and feeds exactly 2 adjacent MFMAs:
//   acc[f]   += frag(t,f) . b_t
//   acc[f+4] += frag(t,f) . b_{t+8}      (f<4)
//   acc[f-4] += frag(t,f) . (-b_{t+8})   (f>=4, sign folded into packed X)
// Swapped MFMA operands (A=W from LDS, B=X): D reg r = out col -> f32x4
// nontemporal stores.
// ---------------------------------------------------------------------------
__global__ __launch_bounds__(512, 4) void analog_fused(const float* __restrict__ X,
                                                       const float* __restrict__ pv,
                                                       float* __restrict__ out) {
    __shared__ __bf16 lw[8 * 8 * 64 * 8];   // 32768 bf16 = 64 KB

    const int tid = threadIdx.x;

    // ---- build t<8 W-fragment half in LDS ----
#pragma unroll
    for (int i = 0; i < 8; ++i) {
        int slot = i * 512 + tid;              // 4096 fragment slots
        int sl = slot & 63, sf = (slot >> 6) & 7, st = slot >> 9;
        int n  = sf * 16 + (sl & 15);
        int sg = sl >> 4;
        float pq = pv[n & 63];
        bool ph  = (n >= 64);
        bf16x8 v;
#pragma unroll
        for (int j = 0; j < 8; ++j) {
            int k = st * 32 + ((j >> 2) << 4) + sg * 4 + (j & 3);   // k < 256
            float arg = pq * (float)k * (-0.0078125f);              // ang / pi
            v[j] = (__bf16)(ph ? sinpif(arg) : cospif(arg));
        }
        *(bf16x8*)(lw + (size_t)slot * 8) = v;
    }
    __syncthreads();

    const int lane = tid & 63;
    const int wave = tid >> 6;        // 0..7
    const int lr   = lane & 15;
    const int g    = lane >> 4;

    const bf16x8* wp = (const bf16x8*)lw + lane;   // + (t*8 + f)*64, t<8

#pragma unroll 1
    for (int s = 0; s < 2; ++s) {
        const long rowbase = (long)blockIdx.x * 256 + (long)s * 128 + (long)wave * 16;
        const float* xp = X + (rowbase + lr) * (long)GK + g * 4;

        f32x4 acc[8];
#pragma unroll
        for (int f = 0; f < 8; ++f) acc[f] = (f32x4)0.0f;

#pragma unroll
        for (int t = 0; t < 8; ++t) {
            f32x4 xa = *(const f32x4*)(xp + t * 32);
            f32x4 xb = *(const f32x4*)(xp + t * 32 + 16);
            f32x4 xc = *(const f32x4*)(xp + (t + 8) * 32);
            f32x4 xd = *(const f32x4*)(xp + (t + 8) * 32 + 16);

            bf16x8 b0, b1;
#pragma unroll
            for (int j = 0; j < 4; ++j) {
                b0[j] = (__bf16)xa[j];  b0[4 + j] = (__bf16)xb[j];
                b1[j] = (__bf16)xc[j];  b1[4 + j] = (__bf16)xd[j];
            }
            u32x4 u = __builtin_bit_cast(u32x4, b1);
#pragma unroll
            for (int j = 0; j < 4; ++j) u[j] ^= 0x80008000u;
            bf16x8 b1n = __builtin_bit_cast(bf16x8, u);

#pragma unroll
            for (int f = 0; f < 8; ++f) {
                bf16x8 w = wp[(t * 8 + f) * 64];
                acc[f] = __builtin_amdgcn_mfma_f32_16x16x32_bf16(w, b0, acc[f], 0, 0, 0);
                if (f < 4)
                    acc[f + 4] = __builtin_amdgcn_mfma_f32_16x16x32_bf16(w, b1, acc[f + 4], 0, 0, 0);
                else
                    acc[f - 4] = __builtin_amdgcn_mfma_f32_16x16x32_bf16(w, b1n, acc[f - 4], 0, 0, 0);
            }
        }

        // lane stores row rowbase+lr, cols f*16 + g*4 .. +3
        float* op = out + (rowbase + lr) * (long)GN + g * 4;
#pragma unroll
        for (int f = 0; f < 8; ++f)
            __builtin_nontemporal_store(acc[f], (f32x4*)(op + f * 16));
    }
}

extern "C" void kernel_launch(void* const* d_in, const int* in_sizes, int n_in,
                              void* d_out, int out_size, void* d_ws, size_t ws_size,
                              hipStream_t stream) {
    const float* x  = (const float*)d_in[0];
    const float* pv = (const float*)d_in[1];
    float* out      = (float*)d_out;

    hipLaunchKernelGGL(analog_fused, dim3(512), dim3(512), 0, stream, x, pv, out);
}

// Round 11
// 180.012 us; speedup vs baseline: 1.0094x; 1.0094x over previous
//
#include <hip/hip_runtime.h>
#include <hip/hip_bf16.h>

#define GK 512
#define GN 128
#define GRROWS 131072   // 4096 batch * 32 blocks

typedef float  f32x4  __attribute__((ext_vector_type(4)));
typedef __bf16 bf16x8 __attribute__((ext_vector_type(8)));
typedef unsigned int u32x4 __attribute__((ext_vector_type(4)));

// ---------------------------------------------------------------------------
// Kernel 1 (R8-proven, unchanged): k<256 half of W in MFMA fragment order.
// wfrag[t][f][lane][j], t=0..7, f=0..7:
//   W[k][n], n = f*16+(lane&15), g=lane>>4, k = t*32+(j>>2)*16+g*4+(j&3)
//   (k-slot permutation applied identically to the X fragment -> contraction
//   unchanged; makes X loads cover full 64B lines)
// W[k][n]=A[n][k]: k<256: n<64 -> cos, n>=64 -> sin (ang=-2pi*pv[n&63]*k/256)
// Symmetry (k->k+256): frag_full(t+8,f) = -frag(t,f+4) [f<4], +frag(t,f-4) [f>=4]
// NOTE: transcendentals live ONLY here (uncapped 256-thr kernel). In-kernel
// sinpif/cospif under a VGPR cap caused the R6/R10 spill catastrophes.
// ---------------------------------------------------------------------------
__global__ void build_w_frags(const float* __restrict__ pv, __bf16* __restrict__ wfrag) {
    int tid = blockIdx.x * blockDim.x + threadIdx.x;
    if (tid >= 8 * 8 * 64) return;
    int lane = tid & 63;
    int f    = (tid >> 6) & 7;
    int t    = tid >> 9;          // 0..7
    int n    = f * 16 + (lane & 15);
    int g    = lane >> 4;
    bool ph  = (n >= 64);
    float pq = pv[n & 63];
    const float step = -0.02454369260617025967f; // -2*pi/256
    bf16x8 v;
#pragma unroll
    for (int j = 0; j < 8; ++j) {
        int k  = t * 32 + ((j >> 2) << 4) + g * 4 + (j & 3);   // k < 256
        float ang = pq * (float)k * step;
        float s, c;
        sincosf(ang, &s, &c);
        v[j] = (__bf16)(ph ? s : c);
    }
    *(bf16x8*)(wfrag + (size_t)tid * 8) = v;
}

// ---------------------------------------------------------------------------
// Kernel 2: R8's proven loop, single-round grid.
// Grid 512 x 512 thr (8 waves) -> exactly 2 blocks/CU, ALL blocks resident in
// one round: W staged once per block, no block-round turnover.
// Each block: 2 stripes of 128 rows (#pragma unroll 1 -> frag ds_reads are
// NOT CSE'd across stripes; acc re-initialized per stripe - R7 lesson).
// Interleaved symmetry (no spill): per t in 0..7, each LDS fragment is read
// once and feeds exactly 2 adjacent MFMAs:
//   acc[f]   += frag(t,f) . b_t
//   acc[f+4] += frag(t,f) . b_{t+8}      (f<4)
//   acc[f-4] += frag(t,f) . (-b_{t+8})   (f>=4, sign folded into packed X)
// Swapped MFMA operands (A=W from LDS, B=X): D reg r = out col -> f32x4
// nontemporal stores.
// ---------------------------------------------------------------------------
__global__ __launch_bounds__(512, 4) void analog_gemm(const float* __restrict__ X,
                                                      const __bf16* __restrict__ W,
                                                      float* __restrict__ out) {
    __shared__ __bf16 lw[8 * 8 * 64 * 8];   // 32768 bf16 = 64 KB

    const int tid = threadIdx.x;

    // Stage W frags global->LDS: 4096 x 16B chunks, 512 thr x 8 each.
    {
        const f32x4* src = (const f32x4*)W;
        f32x4* dst = (f32x4*)lw;
#pragma unroll
        for (int i = 0; i < 8; ++i)
            dst[i * 512 + tid] = src[i * 512 + tid];
    }
    __syncthreads();

    const int lane = tid & 63;
    const int wave = tid >> 6;        // 0..7
    const int lr   = lane & 15;
    const int g    = lane >> 4;

    const bf16x8* wp = (const bf16x8*)lw + lane;   // + (t*8 + f)*64, t<8

#pragma unroll 1
    for (int s = 0; s < 2; ++s) {
        const long rowbase = (long)blockIdx.x * 256 + (long)s * 128 + (long)wave * 16;
        const float* xp = X + (rowbase + lr) * (long)GK + g * 4;

        f32x4 acc[8];
#pragma unroll
        for (int f = 0; f < 8; ++f) acc[f] = (f32x4)0.0f;

#pragma unroll
        for (int t = 0; t < 8; ++t) {
            f32x4 xa = *(const f32x4*)(xp + t * 32);
            f32x4 xb = *(const f32x4*)(xp + t * 32 + 16);
            f32x4 xc = *(const f32x4*)(xp + (t + 8) * 32);
            f32x4 xd = *(const f32x4*)(xp + (t + 8) * 32 + 16);

            bf16x8 b0, b1;
#pragma unroll
            for (int j = 0; j < 4; ++j) {
                b0[j] = (__bf16)xa[j];  b0[4 + j] = (__bf16)xb[j];
                b1[j] = (__bf16)xc[j];  b1[4 + j] = (__bf16)xd[j];
            }
            u32x4 u = __builtin_bit_cast(u32x4, b1);
#pragma unroll
            for (int j = 0; j < 4; ++j) u[j] ^= 0x80008000u;
            bf16x8 b1n = __builtin_bit_cast(bf16x8, u);

#pragma unroll
            for (int f = 0; f < 8; ++f) {
                bf16x8 w = wp[(t * 8 + f) * 64];
                acc[f] = __builtin_amdgcn_mfma_f32_16x16x32_bf16(w, b0, acc[f], 0, 0, 0);
                if (f < 4)
                    acc[f + 4] = __builtin_amdgcn_mfma_f32_16x16x32_bf16(w, b1, acc[f + 4], 0, 0, 0);
                else
                    acc[f - 4] = __builtin_amdgcn_mfma_f32_16x16x32_bf16(w, b1n, acc[f - 4], 0, 0, 0);
            }
        }

        // lane stores row rowbase+lr, cols f*16 + g*4 .. +3
        float* op = out + (rowbase + lr) * (long)GN + g * 4;
#pragma unroll
        for (int f = 0; f < 8; ++f)
            __builtin_nontemporal_store(acc[f], (f32x4*)(op + f * 16));
    }
}

extern "C" void kernel_launch(void* const* d_in, const int* in_sizes, int n_in,
                              void* d_out, int out_size, void* d_ws, size_t ws_size,
                              hipStream_t stream) {
    const float* x  = (const float*)d_in[0];
    const float* pv = (const float*)d_in[1];
    float* out      = (float*)d_out;
    __bf16* wfrag   = (__bf16*)d_ws;   // 8*8*64*8*2 = 65536 bytes used

    hipLaunchKernelGGL(build_w_frags, dim3(16), dim3(256), 0, stream, pv, wfrag);
    hipLaunchKernelGGL(analog_gemm, dim3(512), dim3(512), 0, stream, x, wfrag, out);
}

// Round 12
// 69.404 us; speedup vs baseline: 2.6180x; 2.5937x over previous
//
#include <hip/hip_runtime.h>
#include <hip/hip_bf16.h>

#define GK 512
#define GN 128
#define GRROWS 131072   // 4096 batch * 32 blocks

typedef float  f32x4  __attribute__((ext_vector_type(4)));
typedef __bf16 bf16x8 __attribute__((ext_vector_type(8)));
typedef unsigned int u32x4 __attribute__((ext_vector_type(4)));

// ---------------------------------------------------------------------------
// Kernel 1 (R8-proven, unchanged): k<256 half of W in MFMA fragment order.
// wfrag[t][f][lane][j], t=0..7, f=0..7:
//   W[k][n], n = f*16+(lane&15), g=lane>>4, k = t*32+(j>>2)*16+g*4+(j&3)
//   (k-slot permutation applied identically to the X fragment -> contraction
//   unchanged; makes X loads cover full 64B lines)
// W[k][n]=A[n][k]: k<256: n<64 -> cos, n>=64 -> sin (ang=-2pi*pv[n&63]*k/256)
// Symmetry (k->k+256): frag_full(t+8,f) = -frag(t,f+4) [f<4], +frag(t,f-4) [f>=4]
// Transcendentals live ONLY here (uncapped kernel; R6/R10 lesson).
// ---------------------------------------------------------------------------
__global__ void build_w_frags(const float* __restrict__ pv, __bf16* __restrict__ wfrag) {
    int tid = blockIdx.x * blockDim.x + threadIdx.x;
    if (tid >= 8 * 8 * 64) return;
    int lane = tid & 63;
    int f    = (tid >> 6) & 7;
    int t    = tid >> 9;          // 0..7
    int n    = f * 16 + (lane & 15);
    int g    = lane >> 4;
    bool ph  = (n >= 64);
    float pq = pv[n & 63];
    const float step = -0.02454369260617025967f; // -2*pi/256
    bf16x8 v;
#pragma unroll
    for (int j = 0; j < 8; ++j) {
        int k  = t * 32 + ((j >> 2) << 4) + g * 4 + (j & 3);   // k < 256
        float ang = pq * (float)k * step;
        float s, c;
        sincosf(ang, &s, &c);
        v[j] = (__bf16)(ph ? s : c);
    }
    *(bf16x8*)(wfrag + (size_t)tid * 8) = v;
}

// ---------------------------------------------------------------------------
// Kernel 2: R8's proven loop + single-round grid (512 x 512thr, 2 blocks/CU,
// all resident; W staged once per block). Block covers 2 stripes of 128 rows.
// ANTI-LICM: wp is laundered through an empty asm each stripe iteration so
// the 64 fragment ds_reads CANNOT be hoisted out of the stripe loop (the
// R7/R10/R11 spill mechanism: hoisted frags = 256 VGPRs -> scratch).
// Interleaved symmetry (no spill): per t in 0..7, each LDS fragment is read
// once and feeds exactly 2 adjacent MFMAs:
//   acc[f]   += frag(t,f) . b_t
//   acc[f+4] += frag(t,f) . b_{t+8}      (f<4)
//   acc[f-4] += frag(t,f) . (-b_{t+8})   (f>=4, sign folded into packed X)
// Swapped MFMA operands (A=W from LDS, B=X): D reg r = out col -> f32x4
// nontemporal stores.
// ---------------------------------------------------------------------------
__global__ __launch_bounds__(512, 4) void analog_gemm(const float* __restrict__ X,
                                                      const __bf16* __restrict__ W,
                                                      float* __restrict__ out) {
    __shared__ __bf16 lw[8 * 8 * 64 * 8];   // 32768 bf16 = 64 KB

    const int tid = threadIdx.x;

    // Stage W frags global->LDS: 4096 x 16B chunks, 512 thr x 8 each.
    {
        const f32x4* src = (const f32x4*)W;
        f32x4* dst = (f32x4*)lw;
#pragma unroll
        for (int i = 0; i < 8; ++i)
            dst[i * 512 + tid] = src[i * 512 + tid];
    }
    __syncthreads();

    const int lane = tid & 63;
    const int wave = tid >> 6;        // 0..7
    const int lr   = lane & 15;
    const int g    = lane >> 4;

    const bf16x8* wp = (const bf16x8*)lw + lane;   // + (t*8 + f)*64, t<8

#pragma unroll 1
    for (int s = 0; s < 2; ++s) {
        // Launder the frag pointer: compiler must treat it as stripe-local,
        // so frag ds_reads stay inside the loop (no LICM -> no spill).
        const bf16x8* wps = wp;
        asm volatile("" : "+v"(wps));

        const long rowbase = (long)blockIdx.x * 256 + (long)s * 128 + (long)wave * 16;
        const float* xp = X + (rowbase + lr) * (long)GK + g * 4;

        f32x4 acc[8];
#pragma unroll
        for (int f = 0; f < 8; ++f) acc[f] = (f32x4)0.0f;

#pragma unroll
        for (int t = 0; t < 8; ++t) {
            f32x4 xa = *(const f32x4*)(xp + t * 32);
            f32x4 xb = *(const f32x4*)(xp + t * 32 + 16);
            f32x4 xc = *(const f32x4*)(xp + (t + 8) * 32);
            f32x4 xd = *(const f32x4*)(xp + (t + 8) * 32 + 16);

            bf16x8 b0, b1;
#pragma unroll
            for (int j = 0; j < 4; ++j) {
                b0[j] = (__bf16)xa[j];  b0[4 + j] = (__bf16)xb[j];
                b1[j] = (__bf16)xc[j];  b1[4 + j] = (__bf16)xd[j];
            }
            u32x4 u = __builtin_bit_cast(u32x4, b1);
#pragma unroll
            for (int j = 0; j < 4; ++j) u[j] ^= 0x80008000u;
            bf16x8 b1n = __builtin_bit_cast(bf16x8, u);

#pragma unroll
            for (int f = 0; f < 8; ++f) {
                bf16x8 w = wps[(t * 8 + f) * 64];
                acc[f] = __builtin_amdgcn_mfma_f32_16x16x32_bf16(w, b0, acc[f], 0, 0, 0);
                if (f < 4)
                    acc[f + 4] = __builtin_amdgcn_mfma_f32_16x16x32_bf16(w, b1, acc[f + 4], 0, 0, 0);
                else
                    acc[f - 4] = __builtin_amdgcn_mfma_f32_16x16x32_bf16(w, b1n, acc[f - 4], 0, 0, 0);
            }
        }

        // lane stores row rowbase+lr, cols f*16 + g*4 .. +3
        float* op = out + (rowbase + lr) * (long)GN + g * 4;
#pragma unroll
        for (int f = 0; f < 8; ++f)
            __builtin_nontemporal_store(acc[f], (f32x4*)(op + f * 16));
    }
}

extern "C" void kernel_launch(void* const* d_in, const int* in_sizes, int n_in,
                              void* d_out, int out_size, void* d_ws, size_t ws_size,
                              hipStream_t stream) {
    const float* x  = (const float*)d_in[0];
    const float* pv = (const float*)d_in[1];
    float* out      = (float*)d_out;
    __bf16* wfrag   = (__bf16*)d_ws;   // 8*8*64*8*2 = 65536 bytes used

    hipLaunchKernelGGL(build_w_frags, dim3(16), dim3(256), 0, stream, pv, wfrag);
    hipLaunchKernelGGL(analog_gemm, dim3(512), dim3(512), 0, stream, x, wfrag, out);
}

// Round 15
// 64.529 us; speedup vs baseline: 2.8158x; 1.0755x over previous
//
#include <hip/hip_runtime.h>
#include <hip/hip_bf16.h>

#define GK 512
#define GN 128
#define GRROWS 131072   // 4096 batch * 32 blocks

typedef float  f32x4  __attribute__((ext_vector_type(4)));
typedef __bf16 bf16x8 __attribute__((ext_vector_type(8)));
typedef unsigned int u32x4 __attribute__((ext_vector_type(4)));

// ---------------------------------------------------------------------------
// Kernel 1 (R8-proven, unchanged): k<256 half of W in MFMA fragment order.
// wfrag[t][f][lane][j], t=0..7, f=0..7:
//   W[k][n], n = f*16+(lane&15), g=lane>>4, k = t*32+(j>>2)*16+g*4+(j&3)
//   (k-slot permutation applied identically to the X fragment -> contraction
//   unchanged; makes X loads cover full 64B lines)
// W[k][n]=A[n][k]: k<256: n<64 -> cos, n>=64 -> sin (ang=-2pi*pv[n&63]*k/256)
// Symmetry (k->k+256): frag_full(t+8,f) = -frag(t,f+4) [f<4], +frag(t,f-4) [f>=4]
// NOTE: in-kernel fused W-builds (R13/R14) failed determinism 2/2; W is
// built ONLY here, in its own dispatch (6/6 deterministic).
// ---------------------------------------------------------------------------
__global__ void build_w_frags(const float* __restrict__ pv, __bf16* __restrict__ wfrag) {
    int tid = blockIdx.x * blockDim.x + threadIdx.x;
    if (tid >= 8 * 8 * 64) return;
    int lane = tid & 63;
    int f    = (tid >> 6) & 7;
    int t    = tid >> 9;          // 0..7
    int n    = f * 16 + (lane & 15);
    int g    = lane >> 4;
    bool ph  = (n >= 64);
    float pq = pv[n & 63];
    const float step = -0.02454369260617025967f; // -2*pi/256
    bf16x8 v;
#pragma unroll
    for (int j = 0; j < 8; ++j) {
        int k  = t * 32 + ((j >> 2) << 4) + g * 4 + (j & 3);   // k < 256
        float ang = pq * (float)k * step;
        float s, c;
        sincosf(ang, &s, &c);
        v[j] = (__bf16)(ph ? s : c);
    }
    *(bf16x8*)(wfrag + (size_t)tid * 8) = v;
}

// ---------------------------------------------------------------------------
// Kernel 2: R8 verbatim except __launch_bounds__(512,2) (256-VGPR budget ->
// deeper compiler X-load pipelining; occupancy unchanged: 64KB LDS already
// pins 2 blocks/CU = 4 waves/SIMD).
// Grid 1024 x 512 thr (8 waves); wave = 16 rows x 128 cols, 128 rows/block.
// Interleaved symmetry (no spill): per t in 0..7, each LDS fragment is read
// once and feeds exactly 2 adjacent MFMAs:
//   acc[f]   += frag(t,f) . b_t
//   acc[f+4] += frag(t,f) . b_{t+8}      (f<4)
//   acc[f-4] += frag(t,f) . (-b_{t+8})   (f>=4, sign folded into packed X)
// Swapped MFMA operands (A=W from LDS, B=X): D reg r = out col -> f32x4
// nontemporal stores.
// ---------------------------------------------------------------------------
__global__ __launch_bounds__(512, 2) void analog_gemm(const float* __restrict__ X,
                                                      const __bf16* __restrict__ W,
                                                      float* __restrict__ out) {
    __shared__ __bf16 lw[8 * 8 * 64 * 8];   // 32768 bf16 = 64 KB

    const int tid = threadIdx.x;

    // Stage W frags global->LDS: 4096 x 16B chunks, 512 thr x 8 each.
    {
        const f32x4* src = (const f32x4*)W;
        f32x4* dst = (f32x4*)lw;
#pragma unroll
        for (int i = 0; i < 8; ++i)
            dst[i * 512 + tid] = src[i * 512 + tid];
    }
    __syncthreads();

    const int lane = tid & 63;
    const int wave = tid >> 6;        // 0..7
    const int lr   = lane & 15;
    const int g    = lane >> 4;

    const long rowbase = (long)blockIdx.x * 128 + (long)wave * 16;
    const float* xp = X + (rowbase + lr) * (long)GK + g * 4;
    const bf16x8* wp = (const bf16x8*)lw + lane;   // + (t*8 + f)*64, t<8

    f32x4 acc[8];
#pragma unroll
    for (int f = 0; f < 8; ++f) acc[f] = (f32x4)0.0f;

#pragma unroll
    for (int t = 0; t < 8; ++t) {
        f32x4 xa = *(const f32x4*)(xp + t * 32);
        f32x4 xb = *(const f32x4*)(xp + t * 32 + 16);
        f32x4 xc = *(const f32x4*)(xp + (t + 8) * 32);
        f32x4 xd = *(const f32x4*)(xp + (t + 8) * 32 + 16);

        bf16x8 b0, b1;
#pragma unroll
        for (int j = 0; j < 4; ++j) {
            b0[j] = (__bf16)xa[j];  b0[4 + j] = (__bf16)xb[j];
            b1[j] = (__bf16)xc[j];  b1[4 + j] = (__bf16)xd[j];
        }
        u32x4 u = __builtin_bit_cast(u32x4, b1);
#pragma unroll
        for (int j = 0; j < 4; ++j) u[j] ^= 0x80008000u;
        bf16x8 b1n = __builtin_bit_cast(bf16x8, u);

#pragma unroll
        for (int f = 0; f < 8; ++f) {
            bf16x8 w = wp[(t * 8 + f) * 64];
            acc[f] = __builtin_amdgcn_mfma_f32_16x16x32_bf16(w, b0, acc[f], 0, 0, 0);
            if (f < 4)
                acc[f + 4] = __builtin_amdgcn_mfma_f32_16x16x32_bf16(w, b1, acc[f + 4], 0, 0, 0);
            else
                acc[f - 4] = __builtin_amdgcn_mfma_f32_16x16x32_bf16(w, b1n, acc[f - 4], 0, 0, 0);
        }
    }

    // lane stores row rowbase+lr, cols f*16 + g*4 .. +3
    float* op = out + (rowbase + lr) * (long)GN + g * 4;
#pragma unroll
    for (int f = 0; f < 8; ++f)
        __builtin_nontemporal_store(acc[f], (f32x4*)(op + f * 16));
}

extern "C" void kernel_launch(void* const* d_in, const int* in_sizes, int n_in,
                              void* d_out, int out_size, void* d_ws, size_t ws_size,
                              hipStream_t stream) {
    const float* x  = (const float*)d_in[0];
    const float* pv = (const float*)d_in[1];
    float* out      = (float*)d_out;
    __bf16* wfrag   = (__bf16*)d_ws;   // 8*8*64*8*2 = 65536 bytes used

    hipLaunchKernelGGL(build_w_frags, dim3(16), dim3(256), 0, stream, pv, wfrag);
    hipLaunchKernelGGL(analog_gemm, dim3(GRROWS / 128), dim3(512), 0, stream, x, wfrag, out);
}

// Round 16
// 63.229 us; speedup vs baseline: 2.8737x; 1.0206x over previous
//
#include <hip/hip_runtime.h>
#include <hip/hip_bf16.h>

#define GK 512
#define GN 128
#define GRROWS 131072   // 4096 batch * 32 blocks

typedef float  f32x4  __attribute__((ext_vector_type(4)));
typedef __bf16 bf16x8 __attribute__((ext_vector_type(8)));
typedef unsigned int u32x4 __attribute__((ext_vector_type(4)));

// ---------------------------------------------------------------------------
// FINAL (R8 configuration — session best, 63.6 us, ~89% of the measured
// mixed-stream ceiling for kernel 2 alone).
//
// Kernel 1: k<256 half of W in MFMA fragment order (64 KB).
// wfrag[t][f][lane][j], t=0..7, f=0..7:
//   W[k][n], n = f*16+(lane&15), g=lane>>4, k = t*32+(j>>2)*16+g*4+(j&3)
//   (k-slot permutation applied identically to the X fragment -> contraction
//   unchanged; makes X loads cover full 64B lines)
// W[k][n]=A[n][k]: k<256: n<64 -> cos, n>=64 -> sin (ang=-2pi*pv[n&63]*k/256)
// Symmetry (k->k+256): frag_full(t+8,f) = -frag(t,f+4) [f<4], +frag(t,f-4) [f>=4]
// W built ONLY in its own dispatch: fused in-kernel builds failed the
// harness determinism check 2/2 (R13/R14); two-kernel passed 7/7.
// ---------------------------------------------------------------------------
__global__ void build_w_frags(const float* __restrict__ pv, __bf16* __restrict__ wfrag) {
    int tid = blockIdx.x * blockDim.x + threadIdx.x;
    if (tid >= 8 * 8 * 64) return;
    int lane = tid & 63;
    int f    = (tid >> 6) & 7;
    int t    = tid >> 9;          // 0..7
    int n    = f * 16 + (lane & 15);
    int g    = lane >> 4;
    bool ph  = (n >= 64);
    float pq = pv[n & 63];
    const float step = -0.02454369260617025967f; // -2*pi/256
    bf16x8 v;
#pragma unroll
    for (int j = 0; j < 8; ++j) {
        int k  = t * 32 + ((j >> 2) << 4) + g * 4 + (j & 3);   // k < 256
        float ang = pq * (float)k * step;
        float s, c;
        sincosf(ang, &s, &c);
        v[j] = (__bf16)(ph ? s : c);
    }
    *(bf16x8*)(wfrag + (size_t)tid * 8) = v;
}

// ---------------------------------------------------------------------------
// Kernel 2: grid 1024 x 512 thr (8 waves); wave = 16 rows x 128 cols,
// 128 rows/block; 64 KB LDS -> 2 blocks/CU, 16 waves/CU.
// Interleaved symmetry (no spill; fragment read once, feeds 2 adjacent MFMAs):
//   acc[f]   += frag(t,f) . b_t
//   acc[f+4] += frag(t,f) . b_{t+8}      (f<4)
//   acc[f-4] += frag(t,f) . (-b_{t+8})   (f>=4, sign folded into packed X)
// Swapped MFMA operands (A=W from LDS, B=X): D reg r = out col -> f32x4
// nontemporal stores. X read exactly once (268 MB), out written once (67 MB).
// ---------------------------------------------------------------------------
__global__ __launch_bounds__(512, 4) void analog_gemm(const float* __restrict__ X,
                                                      const __bf16* __restrict__ W,
                                                      float* __restrict__ out) {
    __shared__ __bf16 lw[8 * 8 * 64 * 8];   // 32768 bf16 = 64 KB

    const int tid = threadIdx.x;

    // Stage W frags global->LDS: 4096 x 16B chunks, 512 thr x 8 each.
    {
        const f32x4* src = (const f32x4*)W;
        f32x4* dst = (f32x4*)lw;
#pragma unroll
        for (int i = 0; i < 8; ++i)
            dst[i * 512 + tid] = src[i * 512 + tid];
    }
    __syncthreads();

    const int lane = tid & 63;
    const int wave = tid >> 6;        // 0..7
    const int lr   = lane & 15;
    const int g    = lane >> 4;

    const long rowbase = (long)blockIdx.x * 128 + (long)wave * 16;
    const float* xp = X + (rowbase + lr) * (long)GK + g * 4;
    const bf16x8* wp = (const bf16x8*)lw + lane;   // + (t*8 + f)*64, t<8

    f32x4 acc[8];
#pragma unroll
    for (int f = 0; f < 8; ++f) acc[f] = (f32x4)0.0f;

#pragma unroll
    for (int t = 0; t < 8; ++t) {
        f32x4 xa = *(const f32x4*)(xp + t * 32);
        f32x4 xb = *(const f32x4*)(xp + t * 32 + 16);
        f32x4 xc = *(const f32x4*)(xp + (t + 8) * 32);
        f32x4 xd = *(const f32x4*)(xp + (t + 8) * 32 + 16);

        bf16x8 b0, b1;
#pragma unroll
        for (int j = 0; j < 4; ++j) {
            b0[j] = (__bf16)xa[j];  b0[4 + j] = (__bf16)xb[j];
            b1[j] = (__bf16)xc[j];  b1[4 + j] = (__bf16)xd[j];
        }
        u32x4 u = __builtin_bit_cast(u32x4, b1);
#pragma unroll
        for (int j = 0; j < 4; ++j) u[j] ^= 0x80008000u;
        bf16x8 b1n = __builtin_bit_cast(bf16x8, u);

#pragma unroll
        for (int f = 0; f < 8; ++f) {
            bf16x8 w = wp[(t * 8 + f) * 64];
            acc[f] = __builtin_amdgcn_mfma_f32_16x16x32_bf16(w, b0, acc[f], 0, 0, 0);
            if (f < 4)
                acc[f + 4] = __builtin_amdgcn_mfma_f32_16x16x32_bf16(w, b1, acc[f + 4], 0, 0, 0);
            else
                acc[f - 4] = __builtin_amdgcn_mfma_f32_16x16x32_bf16(w, b1n, acc[f - 4], 0, 0, 0);
        }
    }

    // lane stores row rowbase+lr, cols f*16 + g*4 .. +3
    float* op = out + (rowbase + lr) * (long)GN + g * 4;
#pragma unroll
    for (int f = 0; f < 8; ++f)
        __builtin_nontemporal_store(acc[f], (f32x4*)(op + f * 16));
}

extern "C" void kernel_launch(void* const* d_in, const int* in_sizes, int n_in,
                              void* d_out, int out_size, void* d_ws, size_t ws_size,
                              hipStream_t stream) {
    const float* x  = (const float*)d_in[0];
    const float* pv = (const float*)d_in[1];
    float* out      = (float*)d_out;
    __bf16* wfrag   = (__bf16*)d_ws;   // 8*8*64*8*2 = 65536 bytes used

    hipLaunchKernelGGL(build_w_frags, dim3(16), dim3(256), 0, stream, pv, wfrag);
    hipLaunchKernelGGL(analog_gemm, dim3(GRROWS / 128), dim3(512), 0, stream, x, wfrag, out);
}